// Round 1
// baseline (8570.256 us; speedup 1.0000x reference)
//
#include <hip/hip_runtime.h>

#define NN 100000
#define NE 1600000
#define DF 128

// ---------------- degree ----------------
__global__ void deg_kernel(const int* __restrict__ dst, float* __restrict__ deg) {
    int e = blockIdx.x * blockDim.x + threadIdx.x;
    if (e < NE) atomicAdd(&deg[dst[e]], 1.0f);
}

__global__ void inv_kernel(float* __restrict__ deg) {
    int n = blockIdx.x * blockDim.x + threadIdx.x;
    if (n < NN) deg[n] = 1.0f / fmaxf(deg[n], 1.0f);
}

// ---------------- scatter-add: agg[dst] += h[src], D=128 ----------------
// 32 threads per edge, each thread one float4 (4 scalar atomics)
__global__ void scatter_kernel(const float* __restrict__ h, const int* __restrict__ src,
                               const int* __restrict__ dst, float* __restrict__ agg) {
    int t = blockIdx.x * blockDim.x + threadIdx.x;
    int e = t >> 5;
    if (e >= NE) return;
    int c = (t & 31) << 2;
    int s = src[e];
    int d = dst[e];
    float4 v = *(const float4*)(h + (size_t)s * DF + c);
    float* p = agg + (size_t)d * DF + c;
    atomicAdd(p + 0, v.x);
    atomicAdd(p + 1, v.y);
    atomicAdd(p + 2, v.z);
    atomicAdd(p + 3, v.w);
}

// ---------------- fused SAGE layer GEMM ----------------
// out[r] = [relu]( h[r] @ Ws + (agg[r]*inv[r]) @ Wn + b ),  K = 128, DO in {128, 64}
// block: 256 threads, 64 rows; thread computes RT rows x 4 cols
template <int DO, bool RELU>
__global__ __launch_bounds__(256) void gemm_fused(
    const float* __restrict__ h, const float* __restrict__ agg, const float* __restrict__ inv,
    const float* __restrict__ Ws, const float* __restrict__ Wn, const float* __restrict__ bias,
    float* __restrict__ out) {
    constexpr int TM = 64;
    constexpr int COLG = DO / 4;          // column groups of 4
    constexpr int RT = TM * COLG / 256;   // rows per thread: 8 (DO=128), 4 (DO=64)
    __shared__ float hs[TM][132];         // +4 pad, keeps float4 16B-aligned

    const int tid = threadIdx.x;
    const int tx = tid % COLG;
    const int ty = tid / COLG;
    const int row0 = blockIdx.x * TM;
    const int c0 = tx * 4;

    float4 acc[RT];
#pragma unroll
    for (int i = 0; i < RT; i++) acc[i] = {0.f, 0.f, 0.f, 0.f};

    for (int pass = 0; pass < 2; ++pass) {
        const float* __restrict__ M = pass ? agg : h;
        const float* __restrict__ W = pass ? Wn : Ws;
        __syncthreads();  // protect hs reads of previous pass
        // stage 64x128 tile: 2048 float4, 8 per thread
#pragma unroll
        for (int i = 0; i < 8; ++i) {
            int idx = i * 256 + tid;
            int r = idx >> 5;
            int c = (idx & 31) * 4;
            int gr = row0 + r;
            float4 v = {0.f, 0.f, 0.f, 0.f};
            if (gr < NN) {
                v = *(const float4*)(M + (size_t)gr * DF + c);
                if (pass) {
                    float s = inv[gr];
                    v.x *= s; v.y *= s; v.z *= s; v.w *= s;
                }
            }
            *(float4*)&hs[r][c] = v;
        }
        __syncthreads();

        for (int k = 0; k < DF; k += 4) {
            float4 w0 = *(const float4*)(W + (size_t)(k + 0) * DO + c0);
            float4 w1 = *(const float4*)(W + (size_t)(k + 1) * DO + c0);
            float4 w2 = *(const float4*)(W + (size_t)(k + 2) * DO + c0);
            float4 w3 = *(const float4*)(W + (size_t)(k + 3) * DO + c0);
#pragma unroll
            for (int i = 0; i < RT; i++) {
                int r = ty * RT + i;
                float4 hv = *(const float4*)&hs[r][k];
                acc[i].x += hv.x * w0.x + hv.y * w1.x + hv.z * w2.x + hv.w * w3.x;
                acc[i].y += hv.x * w0.y + hv.y * w1.y + hv.z * w2.y + hv.w * w3.y;
                acc[i].z += hv.x * w0.z + hv.y * w1.z + hv.z * w2.z + hv.w * w3.z;
                acc[i].w += hv.x * w0.w + hv.y * w1.w + hv.z * w2.w + hv.w * w3.w;
            }
        }
    }

    float4 bv = *(const float4*)(bias + c0);
#pragma unroll
    for (int i = 0; i < RT; i++) {
        int gr = row0 + ty * RT + i;
        if (gr < NN) {
            float4 o = acc[i];
            o.x += bv.x; o.y += bv.y; o.z += bv.z; o.w += bv.w;
            if (RELU) {
                o.x = fmaxf(o.x, 0.f); o.y = fmaxf(o.y, 0.f);
                o.z = fmaxf(o.z, 0.f); o.w = fmaxf(o.w, 0.f);
            }
            *(float4*)(out + (size_t)gr * DO + c0) = o;
        }
    }
}

extern "C" void kernel_launch(void* const* d_in, const int* in_sizes, int n_in,
                              void* d_out, int out_size, void* d_ws, size_t ws_size,
                              hipStream_t stream) {
    const float* x   = (const float*)d_in[0];
    const int*   src = (const int*)d_in[1];
    const int*   dst = (const int*)d_in[2];
    const float* Ws0 = (const float*)d_in[3];
    const float* Wn0 = (const float*)d_in[4];
    const float* b0  = (const float*)d_in[5];
    const float* Ws1 = (const float*)d_in[6];
    const float* Wn1 = (const float*)d_in[7];
    const float* b1  = (const float*)d_in[8];
    const float* Ws2 = (const float*)d_in[9];
    const float* Wn2 = (const float*)d_in[10];
    const float* b2  = (const float*)d_in[11];
    float* out = (float*)d_out;

    // workspace layout (floats): inv[N] (padded), h1[N*128], h2[N*128], agg[N*128]
    float* inv = (float*)d_ws;
    float* h1  = inv + 102400;  // N rounded up, keeps 16B alignment
    float* h2  = h1 + (size_t)NN * DF;
    float* agg = h2 + (size_t)NN * DF;

    const size_t aggBytes = (size_t)NN * DF * sizeof(float);
    const int scatterBlocks = (NE * 32) / 256;  // exactly 200000
    const int gemmBlocks = (NN + 63) / 64;      // 1563

    // degree -> inverse (shared by all layers)
    hipMemsetAsync(inv, 0, NN * sizeof(float), stream);
    deg_kernel<<<(NE + 255) / 256, 256, 0, stream>>>(dst, inv);
    inv_kernel<<<(NN + 255) / 256, 256, 0, stream>>>(inv);

    // layer 0: x -> h1
    hipMemsetAsync(agg, 0, aggBytes, stream);
    scatter_kernel<<<scatterBlocks, 256, 0, stream>>>(x, src, dst, agg);
    gemm_fused<128, true><<<gemmBlocks, 256, 0, stream>>>(x, agg, inv, Ws0, Wn0, b0, h1);

    // layer 1: h1 -> h2
    hipMemsetAsync(agg, 0, aggBytes, stream);
    scatter_kernel<<<scatterBlocks, 256, 0, stream>>>(h1, src, dst, agg);
    gemm_fused<128, true><<<gemmBlocks, 256, 0, stream>>>(h1, agg, inv, Ws1, Wn1, b1, h2);

    // layer 2: h2 -> out (no relu)
    hipMemsetAsync(agg, 0, aggBytes, stream);
    scatter_kernel<<<scatterBlocks, 256, 0, stream>>>(h2, src, dst, agg);
    gemm_fused<64, false><<<gemmBlocks, 256, 0, stream>>>(h2, agg, inv, Ws2, Wn2, b2, out);
}

// Round 2
// 923.953 us; speedup vs baseline: 9.2756x; 9.2756x over previous
//
#include <hip/hip_runtime.h>

#define NN 100000
#define NE 1600000
#define DF 128

// ================= CSR build =================

__global__ void deg_int_kernel(const int* __restrict__ dst, int* __restrict__ degi) {
    int e = blockIdx.x * blockDim.x + threadIdx.x;
    if (e < NE) atomicAdd(&degi[dst[e]], 1);
}

// exclusive scan of degi[0..NN) (+ implicit 0 at NN) into rowptr[0..NN]
// K1: per-block (512 elems) Hillis-Steele, write block sums
__global__ void scan1_kernel(const int* __restrict__ degi, int* __restrict__ rowptr,
                             int* __restrict__ aux) {
    __shared__ int sm[512];
    int t = threadIdx.x;
    int g = blockIdx.x * 512 + t;
    int v = (g < NN) ? degi[g] : 0;
    sm[t] = v;
    __syncthreads();
    for (int off = 1; off < 512; off <<= 1) {
        int x = (t >= off) ? sm[t - off] : 0;
        __syncthreads();
        sm[t] += x;
        __syncthreads();
    }
    if (g <= NN) rowptr[g] = sm[t] - v;  // exclusive
    if (t == 511) aux[blockIdx.x] = sm[511];
}

// K2: exclusive scan of the 196 block sums (single block)
__global__ void scan2_kernel(int* __restrict__ aux, int nb) {
    __shared__ int sm[256];
    int t = threadIdx.x;
    int v = (t < nb) ? aux[t] : 0;
    sm[t] = v;
    __syncthreads();
    for (int off = 1; off < 256; off <<= 1) {
        int x = (t >= off) ? sm[t - off] : 0;
        __syncthreads();
        sm[t] += x;
        __syncthreads();
    }
    if (t < nb) aux[t] = sm[t] - v;
}

// K3: add block offsets
__global__ void scan3_kernel(int* __restrict__ rowptr, const int* __restrict__ aux) {
    int g = blockIdx.x * 512 + threadIdx.x;
    if (g <= NN) rowptr[g] += aux[blockIdx.x];
}

// fill col[] grouped by dst (order within a row is arbitrary — sum is commutative)
__global__ void fill_kernel(const int* __restrict__ src, const int* __restrict__ dst,
                            const int* __restrict__ rowptr, int* __restrict__ cnt,
                            int* __restrict__ col) {
    int e = blockIdx.x * blockDim.x + threadIdx.x;
    if (e >= NE) return;
    int d = dst[e];
    int pos = atomicAdd(&cnt[d], 1);
    col[rowptr[d] + pos] = src[e];
}

// ================= gather (mean of neighbor rows), no atomics =================
// one 64-lane wave per dst node, each lane owns a float2 column pair
__global__ __launch_bounds__(256) void gather_kernel(const float* __restrict__ h,
                                                     const int* __restrict__ rowptr,
                                                     const int* __restrict__ col,
                                                     float* __restrict__ mean) {
    int node = blockIdx.x * 4 + (threadIdx.x >> 6);
    if (node >= NN) return;
    int lane = threadIdx.x & 63;
    int s = rowptr[node];
    int e = rowptr[node + 1];
    int c = lane * 2;
    float sx = 0.f, sy = 0.f;
    int j = s;
    for (; j + 1 < e; j += 2) {  // 2-way unroll for load ILP
        int n0 = col[j];
        int n1 = col[j + 1];
        float2 v0 = *(const float2*)(h + (size_t)n0 * DF + c);
        float2 v1 = *(const float2*)(h + (size_t)n1 * DF + c);
        sx += v0.x + v1.x;
        sy += v0.y + v1.y;
    }
    if (j < e) {
        int n0 = col[j];
        float2 v0 = *(const float2*)(h + (size_t)n0 * DF + c);
        sx += v0.x;
        sy += v0.y;
    }
    float invd = 1.f / fmaxf((float)(e - s), 1.f);
    float2 o;
    o.x = sx * invd;
    o.y = sy * invd;
    *(float2*)(mean + (size_t)node * DF + c) = o;
}

// ================= fused SAGE layer GEMM =================
// out[r] = [relu]( h[r] @ Ws + mean[r] @ Wn + b ),  K = 128, DO in {128, 64}
// NOTE: `mean` and `out` may alias (in-place): each block reads only its own
// 64 rows (staged to LDS) before writing them — no __restrict__ on those two.
template <int DO, bool RELU>
__global__ __launch_bounds__(256) void gemm_fused(
    const float* __restrict__ h, const float* mean,
    const float* __restrict__ Ws, const float* __restrict__ Wn,
    const float* __restrict__ bias, float* out) {
    constexpr int TM = 64;
    constexpr int COLG = DO / 4;          // column groups of 4
    constexpr int RT = TM * COLG / 256;   // rows per thread: 8 (DO=128), 4 (DO=64)
    __shared__ float hs[TM][132];         // +4 pad, keeps float4 16B-aligned

    const int tid = threadIdx.x;
    const int tx = tid % COLG;
    const int ty = tid / COLG;
    const int row0 = blockIdx.x * TM;
    const int c0 = tx * 4;

    float4 acc[RT];
#pragma unroll
    for (int i = 0; i < RT; i++) acc[i] = {0.f, 0.f, 0.f, 0.f};

    for (int pass = 0; pass < 2; ++pass) {
        const float* M = pass ? mean : h;
        const float* __restrict__ W = pass ? Wn : Ws;
        __syncthreads();  // protect hs reads of previous pass
#pragma unroll
        for (int i = 0; i < 8; ++i) {  // stage 64x128 tile: 2048 float4
            int idx = i * 256 + tid;
            int r = idx >> 5;
            int c = (idx & 31) * 4;
            int gr = row0 + r;
            float4 v = {0.f, 0.f, 0.f, 0.f};
            if (gr < NN) v = *(const float4*)(M + (size_t)gr * DF + c);
            *(float4*)&hs[r][c] = v;
        }
        __syncthreads();

        for (int k = 0; k < DF; k += 4) {
            float4 w0 = *(const float4*)(W + (size_t)(k + 0) * DO + c0);
            float4 w1 = *(const float4*)(W + (size_t)(k + 1) * DO + c0);
            float4 w2 = *(const float4*)(W + (size_t)(k + 2) * DO + c0);
            float4 w3 = *(const float4*)(W + (size_t)(k + 3) * DO + c0);
#pragma unroll
            for (int i = 0; i < RT; i++) {
                int r = ty * RT + i;
                float4 hv = *(const float4*)&hs[r][k];
                acc[i].x += hv.x * w0.x + hv.y * w1.x + hv.z * w2.x + hv.w * w3.x;
                acc[i].y += hv.x * w0.y + hv.y * w1.y + hv.z * w2.y + hv.w * w3.y;
                acc[i].z += hv.x * w0.z + hv.y * w1.z + hv.z * w2.z + hv.w * w3.z;
                acc[i].w += hv.x * w0.w + hv.y * w1.w + hv.z * w2.w + hv.w * w3.w;
            }
        }
    }

    float4 bv = *(const float4*)(bias + c0);
#pragma unroll
    for (int i = 0; i < RT; i++) {
        int gr = row0 + ty * RT + i;
        if (gr < NN) {
            float4 o = acc[i];
            o.x += bv.x; o.y += bv.y; o.z += bv.z; o.w += bv.w;
            if (RELU) {
                o.x = fmaxf(o.x, 0.f); o.y = fmaxf(o.y, 0.f);
                o.z = fmaxf(o.z, 0.f); o.w = fmaxf(o.w, 0.f);
            }
            *(float4*)(out + (size_t)gr * DO + c0) = o;
        }
    }
}

extern "C" void kernel_launch(void* const* d_in, const int* in_sizes, int n_in,
                              void* d_out, int out_size, void* d_ws, size_t ws_size,
                              hipStream_t stream) {
    const float* x   = (const float*)d_in[0];
    const int*   src = (const int*)d_in[1];
    const int*   dst = (const int*)d_in[2];
    const float* Ws0 = (const float*)d_in[3];
    const float* Wn0 = (const float*)d_in[4];
    const float* b0  = (const float*)d_in[5];
    const float* Ws1 = (const float*)d_in[6];
    const float* Wn1 = (const float*)d_in[7];
    const float* b1  = (const float*)d_in[8];
    const float* Ws2 = (const float*)d_in[9];
    const float* Wn2 = (const float*)d_in[10];
    const float* b2  = (const float*)d_in[11];
    float* out = (float*)d_out;

    // workspace layout (ints then floats), ~110 MB total:
    int* rowptr = (int*)d_ws;                 // N+1 (alloc 100352)
    int* degi   = rowptr + 100352;            // N, reused as cursor for fill
    int* aux    = degi + 100352;              // 1024
    int* col    = aux + 1024;                 // E
    float* A    = (float*)(col + NE);         // N*128  (mean, then h in-place)
    float* B    = A + (size_t)NN * DF;        // N*128

    const int NB = (NN + 1 + 511) / 512;      // 196 scan blocks
    const int gemmBlocks = (NN + 63) / 64;    // 1563
    const int gatherBlocks = (NN + 3) / 4;    // 25000

    // ---- CSR build (per call; ws is re-poisoned every launch) ----
    hipMemsetAsync(degi, 0, NN * sizeof(int), stream);
    deg_int_kernel<<<(NE + 255) / 256, 256, 0, stream>>>(dst, degi);
    scan1_kernel<<<NB, 512, 0, stream>>>(degi, rowptr, aux);
    scan2_kernel<<<1, 256, 0, stream>>>(aux, NB);
    scan3_kernel<<<NB, 512, 0, stream>>>(rowptr, aux);
    hipMemsetAsync(degi, 0, NN * sizeof(int), stream);  // reuse as cursor
    fill_kernel<<<(NE + 255) / 256, 256, 0, stream>>>(src, dst, rowptr, degi, col);

    // ---- layer 0: x -> h1 (in A) ----
    gather_kernel<<<gatherBlocks, 256, 0, stream>>>(x, rowptr, col, A);
    gemm_fused<128, true><<<gemmBlocks, 256, 0, stream>>>(x, A, Ws0, Wn0, b0, A);

    // ---- layer 1: h1 -> h2 (in B) ----
    gather_kernel<<<gatherBlocks, 256, 0, stream>>>(A, rowptr, col, B);
    gemm_fused<128, true><<<gemmBlocks, 256, 0, stream>>>(A, B, Ws1, Wn1, b1, B);

    // ---- layer 2: h2 -> out ----
    gather_kernel<<<gatherBlocks, 256, 0, stream>>>(B, rowptr, col, A);
    gemm_fused<64, false><<<gemmBlocks, 256, 0, stream>>>(B, A, Ws2, Wn2, b2, out);
}

// Round 3
// 823.444 us; speedup vs baseline: 10.4078x; 1.1221x over previous
//
#include <hip/hip_runtime.h>

#define NN 100000
#define NE 1600000
#define DF 128

typedef unsigned int uint32;

// ---- bf16 helpers (round-to-nearest-even) ----
__device__ __forceinline__ float bf2f(uint32 b) {
    union { uint32 u; float f; } v; v.u = b << 16; return v.f;
}
__device__ __forceinline__ uint32 f2bf(float x) {
    union { float f; uint32 u; } v; v.f = x;
    return (v.u + 0x7FFFu + ((v.u >> 16) & 1u)) >> 16;
}

// ================= CSR build =================

__global__ void deg_int_kernel(const int* __restrict__ dst, int* __restrict__ degi) {
    int e = blockIdx.x * blockDim.x + threadIdx.x;
    if (e < NE) atomicAdd(&degi[dst[e]], 1);
}

__global__ void scan1_kernel(const int* __restrict__ degi, int* __restrict__ rowptr,
                             int* __restrict__ aux) {
    __shared__ int sm[512];
    int t = threadIdx.x;
    int g = blockIdx.x * 512 + t;
    int v = (g < NN) ? degi[g] : 0;
    sm[t] = v;
    __syncthreads();
    for (int off = 1; off < 512; off <<= 1) {
        int x = (t >= off) ? sm[t - off] : 0;
        __syncthreads();
        sm[t] += x;
        __syncthreads();
    }
    if (g <= NN) rowptr[g] = sm[t] - v;  // exclusive
    if (t == 511) aux[blockIdx.x] = sm[511];
}

__global__ void scan2_kernel(int* __restrict__ aux, int nb) {
    __shared__ int sm[256];
    int t = threadIdx.x;
    int v = (t < nb) ? aux[t] : 0;
    sm[t] = v;
    __syncthreads();
    for (int off = 1; off < 256; off <<= 1) {
        int x = (t >= off) ? sm[t - off] : 0;
        __syncthreads();
        sm[t] += x;
        __syncthreads();
    }
    if (t < nb) aux[t] = sm[t] - v;
}

__global__ void scan3_kernel(int* __restrict__ rowptr, const int* __restrict__ aux) {
    int g = blockIdx.x * 512 + threadIdx.x;
    if (g <= NN) rowptr[g] += aux[blockIdx.x];
}

__global__ void fill_kernel(const int* __restrict__ src, const int* __restrict__ dst,
                            const int* __restrict__ rowptr, int* __restrict__ cnt,
                            int* __restrict__ col) {
    int e = blockIdx.x * blockDim.x + threadIdx.x;
    if (e >= NE) return;
    int d = dst[e];
    int pos = atomicAdd(&cnt[d], 1);
    col[rowptr[d] + pos] = src[e];
}

// ================= fp32 -> bf16 conversion (x) =================
__global__ void cvt_kernel(const float* __restrict__ x, uint2* __restrict__ xb) {
    int t = blockIdx.x * blockDim.x + threadIdx.x;  // one float4 -> 4 bf16
    if (t < NN * DF / 4) {
        float4 v = ((const float4*)x)[t];
        uint2 o;
        o.x = f2bf(v.x) | (f2bf(v.y) << 16);
        o.y = f2bf(v.z) | (f2bf(v.w) << 16);
        xb[t] = o;
    }
}

// ================= gather mean, bf16 in/out, width 128 =================
// one 64-lane wave per dst node; lane owns 2 bf16 columns (one uint32)
__global__ __launch_bounds__(256) void gather_b16(const uint32* __restrict__ hb,
                                                  const int* __restrict__ rowptr,
                                                  const int* __restrict__ col,
                                                  uint32* __restrict__ mean) {
    int node = blockIdx.x * 4 + (threadIdx.x >> 6);  // grid covers exactly NN
    int lane = threadIdx.x & 63;
    int s = rowptr[node], e = rowptr[node + 1];
    float sx = 0.f, sy = 0.f;
    int j = s;
    for (; j + 3 < e; j += 4) {  // 4-way unroll: 4 outstanding row loads
        int n0 = col[j], n1 = col[j + 1], n2 = col[j + 2], n3 = col[j + 3];
        uint32 u0 = hb[(size_t)n0 * 64 + lane];
        uint32 u1 = hb[(size_t)n1 * 64 + lane];
        uint32 u2 = hb[(size_t)n2 * 64 + lane];
        uint32 u3 = hb[(size_t)n3 * 64 + lane];
        sx += bf2f(u0 & 0xffff) + bf2f(u1 & 0xffff) + bf2f(u2 & 0xffff) + bf2f(u3 & 0xffff);
        sy += bf2f(u0 >> 16) + bf2f(u1 >> 16) + bf2f(u2 >> 16) + bf2f(u3 >> 16);
    }
    for (; j < e; ++j) {
        uint32 u0 = hb[(size_t)col[j] * 64 + lane];
        sx += bf2f(u0 & 0xffff);
        sy += bf2f(u0 >> 16);
    }
    float invd = 1.f / fmaxf((float)(e - s), 1.f);
    mean[(size_t)node * 64 + lane] = f2bf(sx * invd) | (f2bf(sy * invd) << 16);
}

// ================= gather mean-add, bf16 in, width 64, adds into fp32 out ====
__global__ __launch_bounds__(256) void gather_add64(const unsigned short* __restrict__ gb,
                                                    const int* __restrict__ rowptr,
                                                    const int* __restrict__ col,
                                                    float* __restrict__ out) {
    int node = blockIdx.x * 4 + (threadIdx.x >> 6);
    int lane = threadIdx.x & 63;
    int s = rowptr[node], e = rowptr[node + 1];
    float acc = 0.f;
    int j = s;
    for (; j + 3 < e; j += 4) {
        int n0 = col[j], n1 = col[j + 1], n2 = col[j + 2], n3 = col[j + 3];
        acc += bf2f(gb[(size_t)n0 * 64 + lane]) + bf2f(gb[(size_t)n1 * 64 + lane]) +
               bf2f(gb[(size_t)n2 * 64 + lane]) + bf2f(gb[(size_t)n3 * 64 + lane]);
    }
    for (; j < e; ++j) acc += bf2f(gb[(size_t)col[j] * 64 + lane]);
    float invd = 1.f / fmaxf((float)(e - s), 1.f);
    out[(size_t)node * 64 + lane] += acc * invd;
}

// ================= shared GEMM inner loop =================
template <int DO, int RT>
__device__ __forceinline__ void mm_accum(const float (*hs)[132], const float* __restrict__ W,
                                         int c0, int ty, float4* acc) {
    for (int k = 0; k < DF; k += 4) {
        float4 w0 = *(const float4*)(W + (size_t)(k + 0) * DO + c0);
        float4 w1 = *(const float4*)(W + (size_t)(k + 1) * DO + c0);
        float4 w2 = *(const float4*)(W + (size_t)(k + 2) * DO + c0);
        float4 w3 = *(const float4*)(W + (size_t)(k + 3) * DO + c0);
#pragma unroll
        for (int i = 0; i < RT; i++) {
            int r = ty * RT + i;
            float4 hv = *(const float4*)&hs[r][k];
            acc[i].x += hv.x * w0.x + hv.y * w1.x + hv.z * w2.x + hv.w * w3.x;
            acc[i].y += hv.x * w0.y + hv.y * w1.y + hv.z * w2.y + hv.w * w3.y;
            acc[i].z += hv.x * w0.z + hv.y * w1.z + hv.z * w2.z + hv.w * w3.z;
            acc[i].w += hv.x * w0.w + hv.y * w1.w + hv.z * w2.w + hv.w * w3.w;
        }
    }
}

// ================= fused SAGE layer: out = relu(h@Ws + mean@Wn + b) ==========
// h fp32 [N,128]; mean bf16 [N,128]; out fp32 [N,128] (+ optional bf16 copy).
// In-place aliases allowed (out==h, hb16==mean): each block stages its own 64
// rows to LDS (all reads) before the epilogue writes those same rows.
template <bool WB16>
__global__ __launch_bounds__(256) void gemm_fused(
    const float* h, const unsigned short* mean,
    const float* __restrict__ Ws, const float* __restrict__ Wn,
    const float* __restrict__ bias, float* out, unsigned short* hb16) {
    constexpr int DO = 128;
    constexpr int COLG = DO / 4;          // 32
    constexpr int RT = 8;
    __shared__ float hs[64][132];

    const int tid = threadIdx.x;
    const int tx = tid % COLG;
    const int ty = tid / COLG;
    const int row0 = blockIdx.x * 64;
    const int c0 = tx * 4;

    float4 acc[RT];
#pragma unroll
    for (int i = 0; i < RT; i++) acc[i] = {0.f, 0.f, 0.f, 0.f};

    // ---- pass 0: h (fp32) @ Ws ----
#pragma unroll
    for (int i = 0; i < 8; ++i) {
        int idx = i * 256 + tid;
        int r = idx >> 5;
        int c = (idx & 31) * 4;
        int gr = row0 + r;
        float4 v = {0.f, 0.f, 0.f, 0.f};
        if (gr < NN) v = *(const float4*)(h + (size_t)gr * DF + c);
        *(float4*)&hs[r][c] = v;
    }
    __syncthreads();
    mm_accum<DO, RT>(hs, Ws, c0, ty, acc);
    __syncthreads();

    // ---- pass 1: mean (bf16) @ Wn ----
#pragma unroll
    for (int i = 0; i < 8; ++i) {
        int idx = i * 256 + tid;
        int r = idx >> 5;
        int c = (idx & 31) * 4;
        int gr = row0 + r;
        float4 v = {0.f, 0.f, 0.f, 0.f};
        if (gr < NN) {
            uint2 u = *(const uint2*)(mean + (size_t)gr * DF + c);
            v.x = bf2f(u.x & 0xffff); v.y = bf2f(u.x >> 16);
            v.z = bf2f(u.y & 0xffff); v.w = bf2f(u.y >> 16);
        }
        *(float4*)&hs[r][c] = v;
    }
    __syncthreads();
    mm_accum<DO, RT>(hs, Wn, c0, ty, acc);

    // ---- epilogue ----
    float4 bv = *(const float4*)(bias + c0);
#pragma unroll
    for (int i = 0; i < RT; i++) {
        int gr = row0 + ty * RT + i;
        if (gr < NN) {
            float4 o = acc[i];
            o.x = fmaxf(o.x + bv.x, 0.f);
            o.y = fmaxf(o.y + bv.y, 0.f);
            o.z = fmaxf(o.z + bv.z, 0.f);
            o.w = fmaxf(o.w + bv.w, 0.f);
            *(float4*)(out + (size_t)gr * DO + c0) = o;
            if (WB16) {
                uint2 p;
                p.x = f2bf(o.x) | (f2bf(o.y) << 16);
                p.y = f2bf(o.z) | (f2bf(o.w) << 16);
                *(uint2*)(hb16 + (size_t)gr * DO + c0) = p;
            }
        }
    }
}

// ================= single GEMM, DO=64: g = h@W (+b), fp32 or bf16 out =======
template <bool OUTBF16>
__global__ __launch_bounds__(256) void gemm_one(const float* __restrict__ h,
                                                const float* __restrict__ W,
                                                const float* __restrict__ bias,
                                                void* outv) {
    constexpr int DO = 64;
    constexpr int COLG = 16;
    constexpr int RT = 4;
    __shared__ float hs[64][132];

    const int tid = threadIdx.x;
    const int tx = tid % COLG;
    const int ty = tid / COLG;
    const int row0 = blockIdx.x * 64;
    const int c0 = tx * 4;

    float4 acc[RT];
#pragma unroll
    for (int i = 0; i < RT; i++) acc[i] = {0.f, 0.f, 0.f, 0.f};

#pragma unroll
    for (int i = 0; i < 8; ++i) {
        int idx = i * 256 + tid;
        int r = idx >> 5;
        int c = (idx & 31) * 4;
        int gr = row0 + r;
        float4 v = {0.f, 0.f, 0.f, 0.f};
        if (gr < NN) v = *(const float4*)(h + (size_t)gr * DF + c);
        *(float4*)&hs[r][c] = v;
    }
    __syncthreads();
    mm_accum<DO, RT>(hs, W, c0, ty, acc);

#pragma unroll
    for (int i = 0; i < RT; i++) {
        int gr = row0 + ty * RT + i;
        if (gr < NN) {
            float4 o = acc[i];
            if (OUTBF16) {
                uint2 p;
                p.x = f2bf(o.x) | (f2bf(o.y) << 16);
                p.y = f2bf(o.z) | (f2bf(o.w) << 16);
                *(uint2*)((unsigned short*)outv + (size_t)gr * DO + c0) = p;
            } else {
                float4 bv = *(const float4*)(bias + c0);
                o.x += bv.x; o.y += bv.y; o.z += bv.z; o.w += bv.w;
                *(float4*)((float*)outv + (size_t)gr * DO + c0) = o;
            }
        }
    }
}

extern "C" void kernel_launch(void* const* d_in, const int* in_sizes, int n_in,
                              void* d_out, int out_size, void* d_ws, size_t ws_size,
                              hipStream_t stream) {
    const float* x   = (const float*)d_in[0];
    const int*   src = (const int*)d_in[1];
    const int*   dst = (const int*)d_in[2];
    const float* Ws0 = (const float*)d_in[3];
    const float* Wn0 = (const float*)d_in[4];
    const float* b0  = (const float*)d_in[5];
    const float* Ws1 = (const float*)d_in[6];
    const float* Wn1 = (const float*)d_in[7];
    const float* b1  = (const float*)d_in[8];
    const float* Ws2 = (const float*)d_in[9];
    const float* Wn2 = (const float*)d_in[10];
    const float* b2  = (const float*)d_in[11];
    float* out = (float*)d_out;

    // workspace (~109.6 MB):
    //   rowptr[100352] degi[100352] aux[1024] col[NE]
    //   R1: 6.4M uint32 (25.6 MB) = xb -> mean1 -> g2b
    //   R2: 6.4M uint32 (25.6 MB) = mean0 -> h1b (in-place by gemm0)
    //   R3: 12.8M fp32  (51.2 MB) = h1 -> h2 (in-place by gemm1)
    int* rowptr = (int*)d_ws;
    int* degi   = rowptr + 100352;
    int* aux    = degi + 100352;
    int* col    = aux + 1024;
    uint32* R1  = (uint32*)(col + NE);
    uint32* R2  = R1 + (size_t)NN * 64;
    float*  R3  = (float*)(R2 + (size_t)NN * 64);

    const int NB = (NN + 1 + 511) / 512;   // 196
    const int gemmBlocks = (NN + 63) / 64; // 1563

    // ---- CSR build ----
    hipMemsetAsync(degi, 0, NN * sizeof(int), stream);
    deg_int_kernel<<<(NE + 255) / 256, 256, 0, stream>>>(dst, degi);
    scan1_kernel<<<NB, 512, 0, stream>>>(degi, rowptr, aux);
    scan2_kernel<<<1, 256, 0, stream>>>(aux, NB);
    scan3_kernel<<<NB, 512, 0, stream>>>(rowptr, aux);
    hipMemsetAsync(degi, 0, NN * sizeof(int), stream);
    fill_kernel<<<(NE + 255) / 256, 256, 0, stream>>>(src, dst, rowptr, degi, col);

    // ---- x -> bf16 ----
    cvt_kernel<<<(NN * DF / 4 + 255) / 256, 256, 0, stream>>>(x, (uint2*)R1);

    // ---- layer 0: mean0 = gather(xb); h1 = relu(x@Ws0 + mean0@Wn0 + b0) ----
    gather_b16<<<NN / 4, 256, 0, stream>>>(R1, rowptr, col, R2);
    gemm_fused<true><<<gemmBlocks, 256, 0, stream>>>(
        x, (const unsigned short*)R2, Ws0, Wn0, b0, R3, (unsigned short*)R2);

    // ---- layer 1: mean1 = gather(h1b); h2 = relu(h1@Ws1 + mean1@Wn1 + b1) ----
    gather_b16<<<NN / 4, 256, 0, stream>>>(R2, rowptr, col, R1);
    gemm_fused<false><<<gemmBlocks, 256, 0, stream>>>(
        R3, (const unsigned short*)R1, Ws1, Wn1, b1, R3, nullptr);

    // ---- layer 2 (transform-then-aggregate): ----
    // g2 = h2@Wn2 (bf16, width 64); out = h2@Ws2 + b2; out += mean(g2)
    gemm_one<true><<<gemmBlocks, 256, 0, stream>>>(R3, Wn2, nullptr, (void*)R1);
    gemm_one<false><<<gemmBlocks, 256, 0, stream>>>(R3, Ws2, b2, (void*)out);
    gather_add64<<<NN / 4, 256, 0, stream>>>((const unsigned short*)R1, rowptr, col, out);
}

// Round 4
// 645.747 us; speedup vs baseline: 13.2719x; 1.2752x over previous
//
#include <hip/hip_runtime.h>

#define NN 100000
#define NE 1600000
#define DF 128
#define TS 136  // LDS row stride in ushorts: 272 B = 68 banks -> 2-way (free) frag reads

typedef unsigned int uint32;
typedef unsigned short u16;
typedef short s16x8 __attribute__((ext_vector_type(8)));
typedef float f32x4 __attribute__((ext_vector_type(4)));

// ---- bf16 helpers (round-to-nearest-even) ----
__device__ __forceinline__ float bf2f(uint32 b) {
    union { uint32 u; float f; } v; v.u = b << 16; return v.f;
}
__device__ __forceinline__ uint32 f2bf(float x) {
    union { float f; uint32 u; } v; v.f = x;
    return (v.u + 0x7FFFu + ((v.u >> 16) & 1u)) >> 16;
}

// ================= CSR build =================

__global__ void deg_int_kernel(const int* __restrict__ dst, int* __restrict__ degi) {
    int e = blockIdx.x * blockDim.x + threadIdx.x;
    if (e < NE) atomicAdd(&degi[dst[e]], 1);
}

__global__ void scan1_kernel(const int* __restrict__ degi, int* __restrict__ rowptr,
                             int* __restrict__ aux) {
    __shared__ int sm[512];
    int t = threadIdx.x;
    int g = blockIdx.x * 512 + t;
    int v = (g < NN) ? degi[g] : 0;
    sm[t] = v;
    __syncthreads();
    for (int off = 1; off < 512; off <<= 1) {
        int x = (t >= off) ? sm[t - off] : 0;
        __syncthreads();
        sm[t] += x;
        __syncthreads();
    }
    if (g <= NN) rowptr[g] = sm[t] - v;  // exclusive
    if (t == 511) aux[blockIdx.x] = sm[511];
}

__global__ void scan2_kernel(int* __restrict__ aux, int nb) {
    __shared__ int sm[256];
    int t = threadIdx.x;
    int v = (t < nb) ? aux[t] : 0;
    sm[t] = v;
    __syncthreads();
    for (int off = 1; off < 256; off <<= 1) {
        int x = (t >= off) ? sm[t - off] : 0;
        __syncthreads();
        sm[t] += x;
        __syncthreads();
    }
    if (t < nb) aux[t] = sm[t] - v;
}

__global__ void scan3_kernel(int* __restrict__ rowptr, const int* __restrict__ aux) {
    int g = blockIdx.x * 512 + threadIdx.x;
    if (g <= NN) rowptr[g] += aux[blockIdx.x];
}

__global__ void fill_kernel(const int* __restrict__ src, const int* __restrict__ dst,
                            const int* __restrict__ rowptr, int* __restrict__ cnt,
                            int* __restrict__ col) {
    int e = blockIdx.x * blockDim.x + threadIdx.x;
    if (e >= NE) return;
    int d = dst[e];
    int pos = atomicAdd(&cnt[d], 1);
    col[rowptr[d] + pos] = src[e];
}

// ================= x -> bf16 hi/lo split =================
__global__ void cvt_split(const float* __restrict__ x, u16* __restrict__ hi,
                          u16* __restrict__ lo) {
    int t = blockIdx.x * blockDim.x + threadIdx.x;
    if (t < NN * DF / 4) {
        float4 v = ((const float4*)x)[t];
        uint32 h0 = f2bf(v.x), h1 = f2bf(v.y), h2 = f2bf(v.z), h3 = f2bf(v.w);
        uint32 l0 = f2bf(v.x - bf2f(h0)), l1 = f2bf(v.y - bf2f(h1));
        uint32 l2 = f2bf(v.z - bf2f(h2)), l3 = f2bf(v.w - bf2f(h3));
        uint2 ho; ho.x = h0 | (h1 << 16); ho.y = h2 | (h3 << 16);
        uint2 loo; loo.x = l0 | (l1 << 16); loo.y = l2 | (l3 << 16);
        ((uint2*)hi)[t] = ho;
        ((uint2*)lo)[t] = loo;
    }
}

// ================= weight prep: fp32 [k][n] -> bf16 hi/lo transposed [n][k] ====
__global__ void prep_w(const float* __restrict__ W, int DOv, int noff,
                       u16* __restrict__ tHi, u16* __restrict__ tLo) {
    int t = blockIdx.x * blockDim.x + threadIdx.x;
    if (t < 128 * DOv) {
        int k = t / DOv, n = t % DOv;
        float v = W[k * DOv + n];
        uint32 h = f2bf(v);
        float r = v - bf2f(h);
        tHi[(size_t)(n + noff) * 128 + k] = (u16)h;
        tLo[(size_t)(n + noff) * 128 + k] = (u16)f2bf(r);
    }
}

// ================= gathers (unchanged from round 3, proven) =================
__global__ __launch_bounds__(256) void gather_b16(const uint32* __restrict__ hb,
                                                  const int* __restrict__ rowptr,
                                                  const int* __restrict__ col,
                                                  uint32* __restrict__ mean) {
    int node = blockIdx.x * 4 + (threadIdx.x >> 6);
    int lane = threadIdx.x & 63;
    int s = rowptr[node], e = rowptr[node + 1];
    float sx = 0.f, sy = 0.f;
    int j = s;
    for (; j + 3 < e; j += 4) {
        int n0 = col[j], n1 = col[j + 1], n2 = col[j + 2], n3 = col[j + 3];
        uint32 u0 = hb[(size_t)n0 * 64 + lane];
        uint32 u1 = hb[(size_t)n1 * 64 + lane];
        uint32 u2 = hb[(size_t)n2 * 64 + lane];
        uint32 u3 = hb[(size_t)n3 * 64 + lane];
        sx += bf2f(u0 & 0xffff) + bf2f(u1 & 0xffff) + bf2f(u2 & 0xffff) + bf2f(u3 & 0xffff);
        sy += bf2f(u0 >> 16) + bf2f(u1 >> 16) + bf2f(u2 >> 16) + bf2f(u3 >> 16);
    }
    for (; j < e; ++j) {
        uint32 u0 = hb[(size_t)col[j] * 64 + lane];
        sx += bf2f(u0 & 0xffff);
        sy += bf2f(u0 >> 16);
    }
    float invd = 1.f / fmaxf((float)(e - s), 1.f);
    mean[(size_t)node * 64 + lane] = f2bf(sx * invd) | (f2bf(sy * invd) << 16);
}

__global__ __launch_bounds__(256) void gather_add64(const u16* __restrict__ gb,
                                                    const int* __restrict__ rowptr,
                                                    const int* __restrict__ col,
                                                    float* __restrict__ out) {
    int node = blockIdx.x * 4 + (threadIdx.x >> 6);
    int lane = threadIdx.x & 63;
    int s = rowptr[node], e = rowptr[node + 1];
    float acc = 0.f;
    int j = s;
    for (; j + 3 < e; j += 4) {
        int n0 = col[j], n1 = col[j + 1], n2 = col[j + 2], n3 = col[j + 3];
        acc += bf2f(gb[(size_t)n0 * 64 + lane]) + bf2f(gb[(size_t)n1 * 64 + lane]) +
               bf2f(gb[(size_t)n2 * 64 + lane]) + bf2f(gb[(size_t)n3 * 64 + lane]);
    }
    for (; j < e; ++j) acc += bf2f(gb[(size_t)col[j] * 64 + lane]);
    float invd = 1.f / fmaxf((float)(e - s), 1.f);
    out[(size_t)node * 64 + lane] += acc * invd;
}

// ================= MFMA GEMM building blocks =================
// A tile: 128 rows x 128 k (bf16) in LDS, row stride TS.
// B tile: 64 n-rows x 128 k (W^T, bf16) in LDS, row stride TS.
// Fragments per m89/m91-verified layouts: A[m=lane&15][k=(lane>>4)*8+j],
// B[k=(lane>>4)*8+j][n=lane&15], C/D row=(lane>>4)*4+reg, col=lane&15.

__device__ __forceinline__ void stage_a(u16* sm, const u16* g, int row0, int tid) {
#pragma unroll
    for (int i = 0; i < 8; ++i) {  // 128 rows * 16 chunks = 2048; 8/thread
        int idx = i * 256 + tid;
        int r = idx >> 4, c = (idx & 15) * 8;
        uint4 v = make_uint4(0, 0, 0, 0);
        int gr = row0 + r;
        if (gr < NN) v = *(const uint4*)(g + (size_t)gr * DF + c);
        *(uint4*)(sm + r * TS + c) = v;
    }
}

__device__ __forceinline__ void stage_w(u16* sm, const u16* wt, int nbase, int tid) {
#pragma unroll
    for (int i = 0; i < 4; ++i) {  // 64 rows * 16 chunks = 1024; 4/thread
        int idx = i * 256 + tid;
        int r = idx >> 4, c = (idx & 15) * 8;
        *(uint4*)(sm + r * TS + c) = *(const uint4*)(wt + (size_t)(nbase + r) * 128 + c);
    }
}

__device__ __forceinline__ s16x8 frag(const u16* sm, int row, int lane, int kc) {
    return *(const s16x8*)(sm + (row + (lane & 15)) * TS + kc * 32 + (lane >> 4) * 8);
}

// 4 n-tiles (from Bs) x 2 row-tiles x 4 k-chunks = 32 MFMAs
__device__ __forceinline__ void mfma4(const u16* As, const u16* Bs, int wrow, int lane,
                                      f32x4 acc[2][8], int ab) {
    s16x8 a[2][4];
#pragma unroll
    for (int rt = 0; rt < 2; ++rt)
#pragma unroll
        for (int kc = 0; kc < 4; ++kc) a[rt][kc] = frag(As, wrow + rt * 16, lane, kc);
#pragma unroll
    for (int n = 0; n < 4; ++n) {
#pragma unroll
        for (int kc = 0; kc < 4; ++kc) {
            s16x8 b = frag(Bs, n * 16, lane, kc);
            acc[0][ab + n] = __builtin_amdgcn_mfma_f32_16x16x32_bf16(a[0][kc], b, acc[0][ab + n], 0, 0, 0);
            acc[1][ab + n] = __builtin_amdgcn_mfma_f32_16x16x32_bf16(a[1][kc], b, acc[1][ab + n], 0, 0, 0);
        }
    }
}

#define SW(WT, NB) { __syncthreads(); stage_w(Bs, WT, NB, tid); __syncthreads(); }

// ---- fused SAGE layer (DO=128): out = relu(h@Ws + mean@Wn + b), hi/lo bf16 out
// terms: hi@Wsh + hi@Wsl + lo@Wsh (self ~= fp32) ; mean@Wnh + mean@Wnl
// In-place safe: all LDS stagings (reads) happen before the epilogue writes,
// and every block touches only its own 128 rows.
__global__ __launch_bounds__(256) void gemm_sage_mfma(
    const u16* Ahi, const u16* Alo, const u16* Am,
    const u16* __restrict__ Wsh, const u16* __restrict__ Wsl,
    const u16* __restrict__ Wnh, const u16* __restrict__ Wnl,
    const float* __restrict__ bias, u16* OutHi, u16* OutLo) {
    __shared__ u16 As[128 * TS];  // 34816 B
    __shared__ u16 Bs[64 * TS];   // 17408 B -> 52224 total -> 3 blocks/CU
    const int tid = threadIdx.x;
    const int lane = tid & 63;
    const int wrow = (tid >> 6) * 32;
    const int row0 = blockIdx.x * 128;

    f32x4 acc[2][8];
#pragma unroll
    for (int rt = 0; rt < 2; ++rt)
#pragma unroll
        for (int n = 0; n < 8; ++n) acc[rt][n] = {0.f, 0.f, 0.f, 0.f};

    // A = hi : Wsh (both halves), Wsl (both halves)
    stage_a(As, Ahi, row0, tid);
    stage_w(Bs, Wsh, 0, tid);
    __syncthreads();
    mfma4(As, Bs, wrow, lane, acc, 0);
    SW(Wsh, 64); mfma4(As, Bs, wrow, lane, acc, 4);
    SW(Wsl, 0);  mfma4(As, Bs, wrow, lane, acc, 0);
    SW(Wsl, 64); mfma4(As, Bs, wrow, lane, acc, 4);
    // A = lo : Wsh
    __syncthreads();
    stage_a(As, Alo, row0, tid);
    stage_w(Bs, Wsh, 0, tid);
    __syncthreads();
    mfma4(As, Bs, wrow, lane, acc, 0);
    SW(Wsh, 64); mfma4(As, Bs, wrow, lane, acc, 4);
    // A = mean : Wnh, Wnl
    __syncthreads();
    stage_a(As, Am, row0, tid);
    stage_w(Bs, Wnh, 0, tid);
    __syncthreads();
    mfma4(As, Bs, wrow, lane, acc, 0);
    SW(Wnh, 64); mfma4(As, Bs, wrow, lane, acc, 4);
    SW(Wnl, 0);  mfma4(As, Bs, wrow, lane, acc, 0);
    SW(Wnl, 64); mfma4(As, Bs, wrow, lane, acc, 4);

    // epilogue: bias + relu, split hi/lo bf16
    const int cit = lane & 15;
    const int rq = (lane >> 4) * 4;
#pragma unroll
    for (int rt = 0; rt < 2; ++rt)
#pragma unroll
        for (int n = 0; n < 8; ++n) {
            float bv = bias[n * 16 + cit];
            f32x4 v = acc[rt][n];
#pragma unroll
            for (int r = 0; r < 4; ++r) {
                int gr = row0 + wrow + rt * 16 + rq + r;
                if (gr < NN) {
                    float o = fmaxf(v[r] + bv, 0.f);
                    uint32 h = f2bf(o);
                    OutHi[(size_t)gr * DF + n * 16 + cit] = (u16)h;
                    OutLo[(size_t)gr * DF + n * 16 + cit] = (u16)f2bf(o - bf2f(h));
                }
            }
        }
}

// ---- layer 2 (DO=64+64 packed): cols 0-63 -> out=h2@Ws2+b2 (fp32),
//      cols 64-127 -> g2=h2@Wn2 (bf16). No relu. terms: hi@Wh + hi@Wl + lo@Wh.
__global__ __launch_bounds__(256) void gemm_l2_mfma(
    const u16* Ahi, const u16* Alo,
    const u16* __restrict__ Wh, const u16* __restrict__ Wl,
    const float* __restrict__ b2, float* __restrict__ out, u16* __restrict__ g2) {
    __shared__ u16 As[128 * TS];
    __shared__ u16 Bs[64 * TS];
    const int tid = threadIdx.x;
    const int lane = tid & 63;
    const int wrow = (tid >> 6) * 32;
    const int row0 = blockIdx.x * 128;

    f32x4 acc[2][8];
#pragma unroll
    for (int rt = 0; rt < 2; ++rt)
#pragma unroll
        for (int n = 0; n < 8; ++n) acc[rt][n] = {0.f, 0.f, 0.f, 0.f};

    stage_a(As, Ahi, row0, tid);
    stage_w(Bs, Wh, 0, tid);
    __syncthreads();
    mfma4(As, Bs, wrow, lane, acc, 0);
    SW(Wh, 64); mfma4(As, Bs, wrow, lane, acc, 4);
    SW(Wl, 0);  mfma4(As, Bs, wrow, lane, acc, 0);
    SW(Wl, 64); mfma4(As, Bs, wrow, lane, acc, 4);
    __syncthreads();
    stage_a(As, Alo, row0, tid);
    stage_w(Bs, Wh, 0, tid);
    __syncthreads();
    mfma4(As, Bs, wrow, lane, acc, 0);
    SW(Wh, 64); mfma4(As, Bs, wrow, lane, acc, 4);

    const int cit = lane & 15;
    const int rq = (lane >> 4) * 4;
#pragma unroll
    for (int rt = 0; rt < 2; ++rt)
#pragma unroll
        for (int n = 0; n < 8; ++n) {
            f32x4 v = acc[rt][n];
            float bv = (n < 4) ? b2[n * 16 + cit] : 0.f;
#pragma unroll
            for (int r = 0; r < 4; ++r) {
                int gr = row0 + wrow + rt * 16 + rq + r;
                if (gr < NN) {
                    if (n < 4) out[(size_t)gr * 64 + n * 16 + cit] = v[r] + bv;
                    else g2[(size_t)gr * 64 + (n - 4) * 16 + cit] = (u16)f2bf(v[r]);
                }
            }
        }
}

extern "C" void kernel_launch(void* const* d_in, const int* in_sizes, int n_in,
                              void* d_out, int out_size, void* d_ws, size_t ws_size,
                              hipStream_t stream) {
    const float* x   = (const float*)d_in[0];
    const int*   src = (const int*)d_in[1];
    const int*   dst = (const int*)d_in[2];
    const float* Ws0 = (const float*)d_in[3];
    const float* Wn0 = (const float*)d_in[4];
    const float* b0  = (const float*)d_in[5];
    const float* Ws1 = (const float*)d_in[6];
    const float* Wn1 = (const float*)d_in[7];
    const float* b1  = (const float*)d_in[8];
    const float* Ws2 = (const float*)d_in[9];
    const float* Wn2 = (const float*)d_in[10];
    const float* b2  = (const float*)d_in[11];
    float* out = (float*)d_out;

    // workspace (~85 MB): csr misc | col | 10x transposed bf16 weights | P1,P2,P3
    int* rowptr = (int*)d_ws;               // 100352
    int* degi   = rowptr + 100352;          // 100352
    int* aux    = degi + 100352;            // 1024
    int* col    = aux + 1024;               // NE
    u16* WB     = (u16*)(col + NE);         // 10 * 16384 u16
    u16* W0sh = WB,          *W0sl = WB + 16384, *W0nh = WB + 2*16384, *W0nl = WB + 3*16384;
    u16* W1sh = WB + 4*16384, *W1sl = WB + 5*16384, *W1nh = WB + 6*16384, *W1nl = WB + 7*16384;
    u16* W2h  = WB + 8*16384, *W2l  = WB + 9*16384;
    u16* P1 = WB + 10 * 16384;              // xhi -> h1hi -> h2hi
    u16* P2 = P1 + (size_t)NN * DF;         // xlo -> h1lo -> h2lo
    u16* P3 = P2 + (size_t)NN * DF;         // mean0 -> mean1 -> g2

    const int NB = (NN + 1 + 511) / 512;    // 196
    const int gB = (NN + 127) / 128;        // 782 gemm blocks

    // ---- CSR build ----
    hipMemsetAsync(degi, 0, NN * sizeof(int), stream);
    deg_int_kernel<<<(NE + 255) / 256, 256, 0, stream>>>(dst, degi);
    scan1_kernel<<<NB, 512, 0, stream>>>(degi, rowptr, aux);
    scan2_kernel<<<1, 256, 0, stream>>>(aux, NB);
    scan3_kernel<<<NB, 512, 0, stream>>>(rowptr, aux);
    hipMemsetAsync(degi, 0, NN * sizeof(int), stream);
    fill_kernel<<<(NE + 255) / 256, 256, 0, stream>>>(src, dst, rowptr, degi, col);

    // ---- weight prep (split + transpose) ----
    prep_w<<<64, 256, 0, stream>>>(Ws0, 128, 0, W0sh, W0sl);
    prep_w<<<64, 256, 0, stream>>>(Wn0, 128, 0, W0nh, W0nl);
    prep_w<<<64, 256, 0, stream>>>(Ws1, 128, 0, W1sh, W1sl);
    prep_w<<<64, 256, 0, stream>>>(Wn1, 128, 0, W1nh, W1nl);
    prep_w<<<32, 256, 0, stream>>>(Ws2, 64, 0, W2h, W2l);
    prep_w<<<32, 256, 0, stream>>>(Wn2, 64, 64, W2h, W2l);

    // ---- x -> hi/lo bf16 ----
    cvt_split<<<(NN * DF / 4 + 255) / 256, 256, 0, stream>>>(x, P1, P2);

    // ---- layer 0 ----
    gather_b16<<<NN / 4, 256, 0, stream>>>((const uint32*)P1, rowptr, col, (uint32*)P3);
    gemm_sage_mfma<<<gB, 256, 0, stream>>>(P1, P2, P3, W0sh, W0sl, W0nh, W0nl, b0, P1, P2);

    // ---- layer 1 ----
    gather_b16<<<NN / 4, 256, 0, stream>>>((const uint32*)P1, rowptr, col, (uint32*)P3);
    gemm_sage_mfma<<<gB, 256, 0, stream>>>(P1, P2, P3, W1sh, W1sl, W1nh, W1nl, b1, P1, P2);

    // ---- layer 2 (transform-then-aggregate) ----
    gemm_l2_mfma<<<gB, 256, 0, stream>>>(P1, P2, W2h, W2l, b2, out, P3);
    gather_add64<<<NN / 4, 256, 0, stream>>>(P3, rowptr, col, out);
}

// Round 5
// 587.842 us; speedup vs baseline: 14.5792x; 1.0985x over previous
//
#include <hip/hip_runtime.h>

#define NN 100000
#define NE 1600000
#define DF 128
#define TS 136   // LDS row stride in u16: 272 B -> 2-way (free) bank aliasing on frag reads
#define NBK 6250 // dst>>4 buckets, 16 nodes each
#define CAP 768  // bfill LDS segment capacity (bucket avg 256 edges, 22-sigma headroom)

typedef unsigned int uint32;
typedef unsigned short u16;
typedef _Float16 f16;
typedef f16 f16x8 __attribute__((ext_vector_type(8)));
typedef f16 f16x2 __attribute__((ext_vector_type(2)));
typedef float f32x4 __attribute__((ext_vector_type(4)));

// ---- fp16 helpers ----
__device__ __forceinline__ float2 up2(uint32 u) {
    union { uint32 u; f16x2 h; } v; v.u = u;
    return make_float2((float)v.h.x, (float)v.h.y);
}
__device__ __forceinline__ uint32 pk2(float a, float b) {
    union { f16x2 h; uint32 u; } v;
    v.h.x = (f16)a; v.h.y = (f16)b;
    return v.u;
}
__device__ __forceinline__ u16 f2h(float a) {
    union { f16 h; u16 u; } v; v.h = (f16)a; return v.u;
}
__device__ __forceinline__ float h2f(u16 a) {
    union { u16 u; f16 h; } v; v.u = a; return (float)v.h;
}

// ================= bucketed CSR build =================
// bucket b covers dst nodes [b*16, b*16+16); buckets partition dst space in
// order, so bucket streams concatenated ARE the CSR col order.

__global__ void bhist(const int* __restrict__ dst, int* __restrict__ bktcnt) {
    int e = blockIdx.x * 256 + threadIdx.x;
    if (e < NE) atomicAdd(&bktcnt[dst[e] >> 4], 1);
}

// exclusive scan of 6250 bucket counts; writes bktoff, a working copy bktcur,
// and rowptr[NN] = NE
__global__ __launch_bounds__(1024) void bscan(const int* __restrict__ bktcnt,
                                              int* __restrict__ bktoff,
                                              int* __restrict__ bktcur,
                                              int* __restrict__ rowptr) {
    __shared__ int sm[1024];
    int t = threadIdx.x;
    int base = t * 7;
    int loc[7];
    int s = 0;
    for (int i = 0; i < 7; ++i) {
        int b = base + i;
        int v = (b < NBK) ? bktcnt[b] : 0;
        loc[i] = s;  // exclusive within thread
        s += v;
    }
    sm[t] = s;
    __syncthreads();
    for (int off = 1; off < 1024; off <<= 1) {
        int x = (t >= off) ? sm[t - off] : 0;
        __syncthreads();
        sm[t] += x;
        __syncthreads();
    }
    int tb = (t > 0) ? sm[t - 1] : 0;
    for (int i = 0; i < 7; ++i) {
        int b = base + i;
        if (b < NBK) {
            int v = tb + loc[i];
            bktoff[b] = v;
            bktcur[b] = v;
        }
    }
    if (t == 1023) {
        bktoff[NBK] = sm[1023];
        rowptr[NN] = sm[1023];
    }
}

// scatter packed (src<<4 | dst&15) into bucket streams (6250 sequential
// streams -> lines fill before eviction, minimal write amplification)
__global__ void bscatter(const int* __restrict__ src, const int* __restrict__ dst,
                         int* __restrict__ bktcur, uint32* __restrict__ ebuf) {
    int e = blockIdx.x * 256 + threadIdx.x;
    if (e >= NE) return;
    int d = dst[e];
    int pos = atomicAdd(&bktcur[d >> 4], 1);  // already global position
    ebuf[pos] = ((uint32)src[e] << 4) | (uint32)(d & 15);
}

// per-bucket workgroup: LDS histogram over 16 local nodes -> writes rowptr for
// its nodes AND col (sorted within bucket) with fully coalesced stores.
__global__ __launch_bounds__(256) void bfill(const uint32* __restrict__ ebuf,
                                             const int* __restrict__ bktoff,
                                             int* __restrict__ rowptr,
                                             int* __restrict__ col) {
    __shared__ int hist[16], start[16], cur[16];
    __shared__ int seg[CAP];
    int b = blockIdx.x;
    int s = bktoff[b], e = bktoff[b + 1];
    int m = e - s;
    int t = threadIdx.x;
    if (t < 16) { hist[t] = 0; cur[t] = 0; }
    __syncthreads();
    for (int i = t; i < m; i += 256) atomicAdd(&hist[ebuf[s + i] & 15], 1);
    __syncthreads();
    if (t == 0) {
        int acc = 0;
        for (int i = 0; i < 16; ++i) { start[i] = acc; acc += hist[i]; }
    }
    __syncthreads();
    if (t < 16) rowptr[b * 16 + t] = s + start[t];
    if (m <= CAP) {  // fast path (always, in practice): sort into LDS, stream out
        for (int i = t; i < m; i += 256) {
            uint32 u = ebuf[s + i];
            int ld = u & 15;
            int p = atomicAdd(&cur[ld], 1);
            seg[start[ld] + p] = (int)(u >> 4);
        }
        __syncthreads();
        for (int i = t; i < m; i += 256) col[s + i] = seg[i];
    } else {  // correctness fallback for pathological buckets
        for (int i = t; i < m; i += 256) {
            uint32 u = ebuf[s + i];
            int ld = u & 15;
            int p = atomicAdd(&cur[ld], 1);
            col[s + start[ld] + p] = (int)(u >> 4);
        }
    }
}

// ================= weight prep: fp32 [k][n] -> fp16 transposed [n][k] ========
__global__ void prep_w(const float* __restrict__ W, int DOv, int noff,
                       u16* __restrict__ WT) {
    int t = blockIdx.x * 256 + threadIdx.x;
    if (t < 128 * DOv) {
        int k = t / DOv, n = t % DOv;
        WT[(size_t)(n + noff) * 128 + k] = f2h(W[k * DOv + n]);
    }
}

// ================= x -> fp16 =================
__global__ void cvt_f16(const float* __restrict__ x, uint2* __restrict__ xh) {
    int t = blockIdx.x * 256 + threadIdx.x;
    if (t < NN * DF / 4) {
        float4 v = ((const float4*)x)[t];
        uint2 o;
        o.x = pk2(v.x, v.y);
        o.y = pk2(v.z, v.w);
        xh[t] = o;
    }
}

// ================= gather mean, fp16 in/out, width 128 =================
__global__ __launch_bounds__(256) void gather_f16(const uint32* __restrict__ hb,
                                                  const int* __restrict__ rowptr,
                                                  const int* __restrict__ col,
                                                  uint32* __restrict__ mean) {
    int node = blockIdx.x * 4 + (threadIdx.x >> 6);
    int lane = threadIdx.x & 63;
    int s = rowptr[node], e = rowptr[node + 1];
    float sx = 0.f, sy = 0.f;
    int j = s;
    for (; j + 3 < e; j += 4) {
        int n0 = col[j], n1 = col[j + 1], n2 = col[j + 2], n3 = col[j + 3];
        uint32 u0 = hb[(size_t)n0 * 64 + lane];
        uint32 u1 = hb[(size_t)n1 * 64 + lane];
        uint32 u2 = hb[(size_t)n2 * 64 + lane];
        uint32 u3 = hb[(size_t)n3 * 64 + lane];
        float2 a = up2(u0), b = up2(u1), c = up2(u2), d = up2(u3);
        sx += a.x + b.x + c.x + d.x;
        sy += a.y + b.y + c.y + d.y;
    }
    for (; j < e; ++j) {
        float2 a = up2(hb[(size_t)col[j] * 64 + lane]);
        sx += a.x;
        sy += a.y;
    }
    float invd = 1.f / fmaxf((float)(e - s), 1.f);
    mean[(size_t)node * 64 + lane] = pk2(sx * invd, sy * invd);
}

// ================= gather mean-add, fp16 in, width 64, into fp32 out =========
__global__ __launch_bounds__(256) void gather_add_f16(const u16* __restrict__ gb,
                                                      const int* __restrict__ rowptr,
                                                      const int* __restrict__ col,
                                                      float* __restrict__ out) {
    int node = blockIdx.x * 4 + (threadIdx.x >> 6);
    int lane = threadIdx.x & 63;
    int s = rowptr[node], e = rowptr[node + 1];
    float acc = 0.f;
    int j = s;
    for (; j + 3 < e; j += 4) {
        int n0 = col[j], n1 = col[j + 1], n2 = col[j + 2], n3 = col[j + 3];
        acc += h2f(gb[(size_t)n0 * 64 + lane]) + h2f(gb[(size_t)n1 * 64 + lane]) +
               h2f(gb[(size_t)n2 * 64 + lane]) + h2f(gb[(size_t)n3 * 64 + lane]);
    }
    for (; j < e; ++j) acc += h2f(gb[(size_t)col[j] * 64 + lane]);
    float invd = 1.f / fmaxf((float)(e - s), 1.f);
    out[(size_t)node * 64 + lane] += acc * invd;
}

// ================= MFMA GEMM building blocks (fp16, layouts as round 4) ======
__device__ __forceinline__ void stage_a(u16* sm, const u16* g, int row0, int tid) {
#pragma unroll
    for (int i = 0; i < 8; ++i) {
        int idx = i * 256 + tid;
        int r = idx >> 4, c = (idx & 15) * 8;
        uint4 v = make_uint4(0, 0, 0, 0);
        int gr = row0 + r;
        if (gr < NN) v = *(const uint4*)(g + (size_t)gr * DF + c);
        *(uint4*)(sm + r * TS + c) = v;
    }
}

__device__ __forceinline__ void stage_w(u16* sm, const u16* wt, int nbase, int tid) {
#pragma unroll
    for (int i = 0; i < 4; ++i) {
        int idx = i * 256 + tid;
        int r = idx >> 4, c = (idx & 15) * 8;
        *(uint4*)(sm + r * TS + c) = *(const uint4*)(wt + (size_t)(nbase + r) * 128 + c);
    }
}

__device__ __forceinline__ f16x8 frag(const u16* sm, int row, int lane, int kc) {
    return *(const f16x8*)(sm + (row + (lane & 15)) * TS + kc * 32 + (lane >> 4) * 8);
}

__device__ __forceinline__ void mfma4(const u16* As, const u16* Bs, int wrow, int lane,
                                      f32x4 acc[2][8], int ab) {
    f16x8 a[2][4];
#pragma unroll
    for (int rt = 0; rt < 2; ++rt)
#pragma unroll
        for (int kc = 0; kc < 4; ++kc) a[rt][kc] = frag(As, wrow + rt * 16, lane, kc);
#pragma unroll
    for (int n = 0; n < 4; ++n) {
#pragma unroll
        for (int kc = 0; kc < 4; ++kc) {
            f16x8 b = frag(Bs, n * 16, lane, kc);
            acc[0][ab + n] = __builtin_amdgcn_mfma_f32_16x16x32_f16(a[0][kc], b, acc[0][ab + n], 0, 0, 0);
            acc[1][ab + n] = __builtin_amdgcn_mfma_f32_16x16x32_f16(a[1][kc], b, acc[1][ab + n], 0, 0, 0);
        }
    }
}

#define SW(WT, NB) { __syncthreads(); stage_w(Bs, WT, NB, tid); __syncthreads(); }

// ---- fused SAGE layer (DO=128): OutH = fp16(relu(H@Ws + M@Wn + b))
// In-place safe (OutH==H): all H reads happen in the first stage_a, epilogue
// writes only this block's own 128 rows.
__global__ __launch_bounds__(256) void gemm_sage_f16(
    const u16* H, const u16* M,
    const u16* __restrict__ Ws, const u16* __restrict__ Wn,
    const float* __restrict__ bias, u16* OutH) {
    __shared__ u16 As[128 * TS];
    __shared__ u16 Bs[64 * TS];
    const int tid = threadIdx.x;
    const int lane = tid & 63;
    const int wrow = (tid >> 6) * 32;
    const int row0 = blockIdx.x * 128;

    f32x4 acc[2][8];
#pragma unroll
    for (int rt = 0; rt < 2; ++rt)
#pragma unroll
        for (int n = 0; n < 8; ++n) acc[rt][n] = {0.f, 0.f, 0.f, 0.f};

    stage_a(As, H, row0, tid);
    stage_w(Bs, Ws, 0, tid);
    __syncthreads();
    mfma4(As, Bs, wrow, lane, acc, 0);
    SW(Ws, 64); mfma4(As, Bs, wrow, lane, acc, 4);
    __syncthreads();
    stage_a(As, M, row0, tid);
    stage_w(Bs, Wn, 0, tid);
    __syncthreads();
    mfma4(As, Bs, wrow, lane, acc, 0);
    SW(Wn, 64); mfma4(As, Bs, wrow, lane, acc, 4);

    const int cit = lane & 15;
    const int rq = (lane >> 4) * 4;
#pragma unroll
    for (int rt = 0; rt < 2; ++rt)
#pragma unroll
        for (int n = 0; n < 8; ++n) {
            float bv = bias[n * 16 + cit];
            f32x4 v = acc[rt][n];
#pragma unroll
            for (int r = 0; r < 4; ++r) {
                int gr = row0 + wrow + rt * 16 + rq + r;
                if (gr < NN) {
                    float o = fmaxf(v[r] + bv, 0.f);
                    OutH[(size_t)gr * DF + n * 16 + cit] = f2h(o);
                }
            }
        }
}

// ---- layer 2 (128 packed cols): n 0-63 -> out = H@Ws2 + b2 (fp32);
//      n 64-127 -> g2 = H@Wn2 (fp16). W2 rows 0-63 = Ws2^T, 64-127 = Wn2^T.
__global__ __launch_bounds__(256) void gemm_l2_f16(
    const u16* __restrict__ H, const u16* __restrict__ W2,
    const float* __restrict__ b2, float* __restrict__ out, u16* __restrict__ g2) {
    __shared__ u16 As[128 * TS];
    __shared__ u16 Bs[64 * TS];
    const int tid = threadIdx.x;
    const int lane = tid & 63;
    const int wrow = (tid >> 6) * 32;
    const int row0 = blockIdx.x * 128;

    f32x4 acc[2][8];
#pragma unroll
    for (int rt = 0; rt < 2; ++rt)
#pragma unroll
        for (int n = 0; n < 8; ++n) acc[rt][n] = {0.f, 0.f, 0.f, 0.f};

    stage_a(As, H, row0, tid);
    stage_w(Bs, W2, 0, tid);
    __syncthreads();
    mfma4(As, Bs, wrow, lane, acc, 0);
    SW(W2, 64); mfma4(As, Bs, wrow, lane, acc, 4);

    const int cit = lane & 15;
    const int rq = (lane >> 4) * 4;
#pragma unroll
    for (int rt = 0; rt < 2; ++rt)
#pragma unroll
        for (int n = 0; n < 8; ++n) {
            f32x4 v = acc[rt][n];
            float bv = (n < 4) ? b2[n * 16 + cit] : 0.f;
#pragma unroll
            for (int r = 0; r < 4; ++r) {
                int gr = row0 + wrow + rt * 16 + rq + r;
                if (gr < NN) {
                    if (n < 4) out[(size_t)gr * 64 + n * 16 + cit] = v[r] + bv;
                    else g2[(size_t)gr * 64 + (n - 4) * 16 + cit] = f2h(v[r]);
                }
            }
        }
}

extern "C" void kernel_launch(void* const* d_in, const int* in_sizes, int n_in,
                              void* d_out, int out_size, void* d_ws, size_t ws_size,
                              hipStream_t stream) {
    const float* x   = (const float*)d_in[0];
    const int*   src = (const int*)d_in[1];
    const int*   dst = (const int*)d_in[2];
    const float* Ws0 = (const float*)d_in[3];
    const float* Wn0 = (const float*)d_in[4];
    const float* b0  = (const float*)d_in[5];
    const float* Ws1 = (const float*)d_in[6];
    const float* Wn1 = (const float*)d_in[7];
    const float* b1  = (const float*)d_in[8];
    const float* Ws2 = (const float*)d_in[9];
    const float* Wn2 = (const float*)d_in[10];
    const float* b2  = (const float*)d_in[11];
    float* out = (float*)d_out;

    // workspace (~65 MB):
    int* bktcnt  = (int*)d_ws;                 // 6400
    int* bktoff  = bktcnt + 6400;              // 6400 (NBK+1)
    int* bktcur  = bktoff + 6400;              // 6400
    int* rowptr  = bktcur + 6400;              // 100352 (NN+1)
    int* col     = rowptr + 100352;            // NE
    uint32* ebuf = (uint32*)(col + NE);        // NE
    u16* WB      = (u16*)(ebuf + NE);          // 5 * 16384
    u16* W0s = WB, *W0n = WB + 16384, *W1s = WB + 2 * 16384, *W1n = WB + 3 * 16384;
    u16* W2  = WB + 4 * 16384;
    u16* P1 = WB + 5 * 16384;                  // fp16 x -> h1 -> h2 (in-place)
    u16* P3 = P1 + (size_t)NN * DF;            // fp16 mean0 -> mean1 -> g2

    const int gB = (NN + 127) / 128;           // 782

    // ---- bucketed CSR build ----
    hipMemsetAsync(bktcnt, 0, NBK * sizeof(int), stream);
    bhist<<<NE / 256, 256, 0, stream>>>(dst, bktcnt);
    bscan<<<1, 1024, 0, stream>>>(bktcnt, bktoff, bktcur, rowptr);
    bscatter<<<NE / 256, 256, 0, stream>>>(src, dst, bktcur, ebuf);
    bfill<<<NBK, 256, 0, stream>>>(ebuf, bktoff, rowptr, col);

    // ---- weight prep (fp16, transposed) ----
    prep_w<<<64, 256, 0, stream>>>(Ws0, 128, 0, W0s);
    prep_w<<<64, 256, 0, stream>>>(Wn0, 128, 0, W0n);
    prep_w<<<64, 256, 0, stream>>>(Ws1, 128, 0, W1s);
    prep_w<<<64, 256, 0, stream>>>(Wn1, 128, 0, W1n);
    prep_w<<<32, 256, 0, stream>>>(Ws2, 64, 0, W2);
    prep_w<<<32, 256, 0, stream>>>(Wn2, 64, 64, W2);

    // ---- x -> fp16 ----
    cvt_f16<<<NN * DF / 4 / 256, 256, 0, stream>>>(x, (uint2*)P1);

    // ---- layer 0 ----
    gather_f16<<<NN / 4, 256, 0, stream>>>((const uint32*)P1, rowptr, col, (uint32*)P3);
    gemm_sage_f16<<<gB, 256, 0, stream>>>(P1, P3, W0s, W0n, b0, P1);

    // ---- layer 1 ----
    gather_f16<<<NN / 4, 256, 0, stream>>>((const uint32*)P1, rowptr, col, (uint32*)P3);
    gemm_sage_f16<<<gB, 256, 0, stream>>>(P1, P3, W1s, W1n, b1, P1);

    // ---- layer 2 (transform-then-aggregate) ----
    gemm_l2_f16<<<gB, 256, 0, stream>>>(P1, W2, b2, out, P3);
    gather_add_f16<<<NN / 4, 256, 0, stream>>>(P3, rowptr, col, out);
}